// Round 8
// baseline (516.273 us; speedup 1.0000x reference)
//
#include <hip/hip_runtime.h>
#include <hip/hip_bf16.h>
#include <math.h>

// Problem dims
#define B_   32
#define NO_  100
#define NE_  600
#define NK_  1000
#define KE_  1000
#define L_   8
#define R_   8
#define H_   512
#define IMG_ 2048
#define LOC_ 5
#define EMB_ 300
#define MID_ 512
#define C_   3000
#define PAD_ 1

#define NN_  (NO_ + NK_)   // 1100 node keys
#define NEK_ (NE_ + KE_)   // 1600 edge keys

typedef __attribute__((ext_vector_type(8))) short bf16x8;
typedef __attribute__((ext_vector_type(4))) float f32x4;

__device__ __forceinline__ float4 ldf4(const float* p) { return *(const float4*)p; }

__device__ __forceinline__ float bf2f(short s) {
    unsigned u = ((unsigned)(unsigned short)s) << 16;
    float f; __builtin_memcpy(&f, &u, 4); return f;
}
__device__ __forceinline__ short f2bf(float f) {
    unsigned u; __builtin_memcpy(&u, &f, 4);
    u = (u + 0x7fffu + ((u >> 16) & 1u)) >> 16;   // round-nearest-even
    return (short)u;
}

// Direct global->LDS 16B/lane. LDS dest must be wave-uniform; HW writes
// dest + lane*16. Global src is per-lane.
__device__ __forceinline__ void gload16(const void* g, void* l) {
    __builtin_amdgcn_global_load_lds(
        (__attribute__((address_space(1))) void*)(g),
        (__attribute__((address_space(3))) void*)(l), 16, 0, 0);
}

// ---------------------------------------------------------------------------
// W_prep: f32 W[K][512] -> bf16 tiles [NB=4][KS][4 kg][128 nl][8 j]
// entry = W[ks*32+kg*8+j][nb*128+nl]  (zeros for k >= K)
__global__ __launch_bounds__(256) void wprep_kernel(
    const float* __restrict__ W, short* __restrict__ Wp, int K, int KS)
{
    int idx = blockIdx.x * 256 + threadIdx.x;
    int total = 4 * KS * 4 * 128;
    if (idx >= total) return;
    int nl = idx & 127;
    int kg = (idx >> 7) & 3;
    int t  = idx >> 9;            // nb*KS + ks
    int ks = t % KS;
    int nb = t / KS;
    int n = nb * 128 + nl;
    short o[8];
#pragma unroll
    for (int j = 0; j < 8; ++j) {
        int k = ks * 32 + kg * 8 + j;
        o[j] = (k < K) ? f2bf(W[(long)k * H_ + n]) : (short)0;
    }
    *(uint4*)&Wp[(long)idx * 8] = *(uint4*)o;
}

// f32 -> bf16 elementwise (n multiple of 8)
__global__ __launch_bounds__(256) void cvt_bf16_kernel(
    const float* __restrict__ src, short* __restrict__ dst, long n)
{
    long i = ((long)blockIdx.x * 256 + threadIdx.x) * 8;
    if (i >= n) return;
    float4 a = ldf4(src + i), b = ldf4(src + i + 4);
    short o[8] = { f2bf(a.x), f2bf(a.y), f2bf(a.z), f2bf(a.w),
                   f2bf(b.x), f2bf(b.y), f2bf(b.z), f2bf(b.w) };
    *(uint4*)&dst[i] = *(uint4*)o;
}

// ---------------------------------------------------------------------------
// Pool: masked mean of bf16 embeddings. 32 rows/block, minimal LDS, high
// occupancy to hide random-gather latency. Writes pooled [row][320] bf16
// (zeros past EMB and for rows >= nrows) + optional "any != PAD" mask.
__global__ __launch_bounds__(256) void pool_kernel(
    const int* __restrict__ tokens, int tok_stride, int tok_off,
    const short* __restrict__ embed_bf, short* __restrict__ pooled,
    float* __restrict__ maskout, int nrows)
{
    __shared__ int   toks[32][8];
    __shared__ float rinv[32];
    int tid = threadIdx.x, base = blockIdx.x * 32;
    {
        int r = tid >> 3, t = tid & 7;
        int i = base + r;
        toks[r][t] = (i < nrows) ? tokens[tok_off + (long)i * tok_stride + t] : PAD_;
    }
    __syncthreads();
    if (tid < 32) {
        int c = 0;
#pragma unroll
        for (int t = 0; t < 8; ++t) c += (toks[tid][t] != PAD_);
        rinv[tid] = 1.0f / fmaxf((float)c, 1.0f);
        int i = base + tid;
        if (maskout && i < nrows) maskout[i] = (c > 0) ? 1.0f : 0.0f;
    }
    __syncthreads();

    for (int task = tid; task < 32 * 40; task += 256) {
        int r = task / 40, kg = task - r * 40;    // row, 8-elem chunk
        float s[8] = {0.f,0.f,0.f,0.f,0.f,0.f,0.f,0.f};
        if (kg < 38) {                            // EMB=300 -> chunks 0..37
#pragma unroll
            for (int t = 0; t < 8; ++t) {
                int tok = toks[r][t];
                if (tok != PAD_) {
                    bf16x8 e = *(const bf16x8*)&embed_bf[(long)tok * EMB_ + kg * 8];
#pragma unroll
                    for (int j = 0; j < 8; ++j) s[j] += bf2f(e[j]);
                }
            }
        }
        float iv = rinv[r];
        short o[8];
#pragma unroll
        for (int j = 0; j < 8; ++j) {
            float v = s[j] * iv;
            if (kg == 37 && j >= 4) v = 0.f;      // elems 300..303 are overread
            o[j] = f2bf(v);
        }
        *(uint4*)&pooled[(long)(base + r) * 320 + kg * 8] = *(uint4*)o;
    }
}

// ---------------------------------------------------------------------------
// Keys GEMM: pooled[rows][320] @ W_lang (KS=10) -> tanh(+bias) -> out.
// 128x128 tile, 4 waves; double-buffered LDS + global_load_lds staging,
// one barrier per K-step.
template<int OUTF32>
__global__ __launch_bounds__(256) void keys_gemm_kernel(
    const short* __restrict__ A, const short* __restrict__ Wp,
    const float* __restrict__ bias,
    void* __restrict__ out, int rows_per_b, long out_bstride, long out_roff,
    int nrows)
{
    const int KS = 10;
    __shared__ __align__(16) short As[2 * 4096];   // [buf][4 kg][128 row][8]
    __shared__ __align__(16) short Bs[2 * 4096];   // [buf][4 kg][128 nl][8]
    int tid = threadIdx.x;
    int m0 = blockIdx.x * 128, nb = blockIdx.y, n0 = nb * 128;
    int w = tid >> 6, l = tid & 63, wr = w >> 1, wc = w & 1;
    const short* wslab = Wp + (long)nb * KS * 4096;

    auto stage = [&](int buf, int ks) {
        short* Ad = As + buf * 4096 + w * 1024;
        short* Bd = Bs + buf * 4096 + w * 1024;
        const short* bsrc = wslab + (long)ks * 4096 + w * 1024 + l * 8;
#pragma unroll
        for (int i = 0; i < 2; ++i) {
            const short* ga = A + (long)(m0 + i * 64 + l) * 320 + ks * 32 + w * 8;
            gload16(ga, Ad + i * 512);
            gload16(bsrc + i * 512, Bd + i * 512);
        }
    };

    f32x4 acc[4][4];
#pragma unroll
    for (int m = 0; m < 4; ++m)
#pragma unroll
        for (int n = 0; n < 4; ++n)
#pragma unroll
            for (int k = 0; k < 4; ++k) acc[m][n][k] = 0.f;

    int kg = l >> 4, li = l & 15;
    stage(0, 0);
    __syncthreads();
    int buf = 0;
    for (int ks = 0; ks < KS; ++ks) {
        if (ks + 1 < KS) stage(buf ^ 1, ks + 1);   // issue next tile early
        bf16x8 af[4], bfr[4];
#pragma unroll
        for (int m = 0; m < 4; ++m)
            af[m] = *(const bf16x8*)&As[buf * 4096 + kg * 1024 + (wr * 64 + m * 16 + li) * 8];
#pragma unroll
        for (int n = 0; n < 4; ++n)
            bfr[n] = *(const bf16x8*)&Bs[buf * 4096 + kg * 1024 + (wc * 64 + n * 16 + li) * 8];
#pragma unroll
        for (int m = 0; m < 4; ++m)
#pragma unroll
            for (int n = 0; n < 4; ++n)
                acc[m][n] = __builtin_amdgcn_mfma_f32_16x16x32_bf16(af[m], bfr[n], acc[m][n], 0, 0, 0);
        __syncthreads();                            // drains vmcnt + lgkmcnt
        buf ^= 1;
    }

    int jrow4 = (l >> 4) * 4;
    float bv[4];
#pragma unroll
    for (int n = 0; n < 4; ++n) bv[n] = bias[n0 + wc * 64 + n * 16 + li];
#pragma unroll
    for (int m = 0; m < 4; ++m)
#pragma unroll
        for (int j = 0; j < 4; ++j) {
            int i = m0 + wr * 64 + m * 16 + jrow4 + j;
            if (i >= nrows) continue;
            int b = i / rows_per_b, k = i - b * rows_per_b;
#pragma unroll
            for (int n = 0; n < 4; ++n) {
                int col = n0 + wc * 64 + n * 16 + li;
                float val = tanhf(acc[m][n][j] + bv[n]);
                long idx = (long)b * out_bstride + out_roff + (long)k * H_ + col;
                if (OUTF32) ((float*)out)[idx] = val;
                else        ((short*)out)[idx] = f2bf(val);
            }
        }
}

// ---------------------------------------------------------------------------
// MFMA GEMM: 128x128 tile, BK=32, 4 waves each owning 64x64; grid (nrb, 4).
// Double-buffered LDS + global_load_lds staging, one barrier per K-step.
// A: bf16 row-major (AV=0) or gathered img_f rows (AV=2, K=1024 two halves).
// EP: 0 img_node (img_f + node_keys w/ loc), 1 img_edge, 2 score partials.
template<int AV, int EP, int KS>
__global__ __launch_bounds__(256) void mfma_gemm_kernel(
    const short* __restrict__ A, int lda, const short* __restrict__ Wp,
    const int* __restrict__ id1, const int* __restrict__ id2,
    const short* __restrict__ Agather,
    const float* __restrict__ bias, const float* __restrict__ bias2,
    const float* __restrict__ loc, const float* __restrict__ Wloc,
    const float* __restrict__ qp, const float* __restrict__ vvec,
    short* __restrict__ out0, short* __restrict__ out1,
    float* __restrict__ sout, int Nrows, int Mtot)
{
    __shared__ __align__(16) short As[2 * 4096];   // [buf][4 kg][128 row][8]
    __shared__ __align__(16) short Bs[2 * 4096];   // [buf][4 kg][128 nl][8]
    int tid = threadIdx.x;
    int m0 = blockIdx.x * 128, nb = blockIdx.y, n0 = nb * 128;
    int w = tid >> 6, l = tid & 63, wr = w >> 1, wc = w & 1;

    int r1[2], r2[2];                               // AV=2 gathered rows
    if (AV == 2) {
#pragma unroll
        for (int i = 0; i < 2; ++i) {
            int row = m0 + i * 64 + l;
            int b = row / NE_;
            r1[i] = b * NO_ + id1[row];
            r2[i] = b * NO_ + id2[row];
        }
    }
    const short* wslab = Wp + (long)nb * KS * 4096;

    auto stage = [&](int buf, int ks) {
        short* Ad = As + buf * 4096 + w * 1024;
        short* Bd = Bs + buf * 4096 + w * 1024;
        const short* bsrc = wslab + (long)ks * 4096 + w * 1024 + l * 8;
#pragma unroll
        for (int i = 0; i < 2; ++i) {
            const short* ga;
            if (AV == 0) {
                ga = A + (long)(m0 + i * 64 + l) * lda + ks * 32 + w * 8;
            } else {
                int kk = ks * 32;
                int row = (kk < 512) ? r1[i] : r2[i];
                ga = Agather + (long)row * 512 + (kk & 511) + w * 8;
            }
            gload16(ga, Ad + i * 512);
            gload16(bsrc + i * 512, Bd + i * 512);
        }
    };

    f32x4 acc[4][4];
#pragma unroll
    for (int m = 0; m < 4; ++m)
#pragma unroll
        for (int n = 0; n < 4; ++n)
#pragma unroll
            for (int k = 0; k < 4; ++k) acc[m][n][k] = 0.f;

    int kg = l >> 4, li = l & 15;
    stage(0, 0);
    __syncthreads();
    int buf = 0;
    for (int ks = 0; ks < KS; ++ks) {
        if (ks + 1 < KS) stage(buf ^ 1, ks + 1);   // issue next tile early
        bf16x8 af[4], bfr[4];
#pragma unroll
        for (int m = 0; m < 4; ++m)
            af[m] = *(const bf16x8*)&As[buf * 4096 + kg * 1024 + (wr * 64 + m * 16 + li) * 8];
#pragma unroll
        for (int n = 0; n < 4; ++n)
            bfr[n] = *(const bf16x8*)&Bs[buf * 4096 + kg * 1024 + (wc * 64 + n * 16 + li) * 8];
#pragma unroll
        for (int m = 0; m < 4; ++m)
#pragma unroll
            for (int n = 0; n < 4; ++n)
                acc[m][n] = __builtin_amdgcn_mfma_f32_16x16x32_bf16(af[m], bfr[n], acc[m][n], 0, 0, 0);
        __syncthreads();                            // drains vmcnt + lgkmcnt
        buf ^= 1;
    }

    int jrow4 = (l >> 4) * 4;
    if (EP == 0) {                             // img_node
        float bi[4], bl[4], wl[4][5];
#pragma unroll
        for (int n = 0; n < 4; ++n) {
            int col = n0 + wc * 64 + n * 16 + li;
            bi[n] = bias[col]; bl[n] = bias2[col];
#pragma unroll
            for (int j5 = 0; j5 < 5; ++j5) wl[n][j5] = Wloc[j5 * H_ + col];
        }
#pragma unroll
        for (int m = 0; m < 4; ++m)
#pragma unroll
            for (int j = 0; j < 4; ++j) {
                int row = m0 + wr * 64 + m * 16 + jrow4 + j;
                int b = row / NO_, o = row - b * NO_;
                float lv[5];
#pragma unroll
                for (int j5 = 0; j5 < 5; ++j5) lv[j5] = loc[(long)row * 5 + j5];
#pragma unroll
                for (int n = 0; n < 4; ++n) {
                    int col = n0 + wc * 64 + n * 16 + li;
                    float val = acc[m][n][j] + bi[n];
                    out0[(long)row * H_ + col] = f2bf(val);
                    float nk = val + bl[n];
#pragma unroll
                    for (int j5 = 0; j5 < 5; ++j5) nk = fmaf(lv[j5], wl[n][j5], nk);
                    out1[((long)b * NN_ + o) * H_ + col] = f2bf(nk);
                }
            }
    } else if (EP == 1) {                      // img_edge
        float bi[4];
#pragma unroll
        for (int n = 0; n < 4; ++n) bi[n] = bias[n0 + wc * 64 + n * 16 + li];
#pragma unroll
        for (int m = 0; m < 4; ++m)
#pragma unroll
            for (int j = 0; j < 4; ++j) {
                int row = m0 + wr * 64 + m * 16 + jrow4 + j;
                int b = row / NE_, e = row - b * NE_;
#pragma unroll
                for (int n = 0; n < 4; ++n) {
                    int col = n0 + wc * 64 + n * 16 + li;
                    out0[((long)b * NEK_ + e) * H_ + col] = f2bf(acc[m][n][j] + bi[n]);
                }
            }
    } else {                                   // score partials
        float vv[4];
        int cols[4];
#pragma unroll
        for (int n = 0; n < 4; ++n) {
            cols[n] = n0 + wc * 64 + n * 16 + li;
            vv[n] = vvec[cols[n]];
        }
        int slot = nb * 2 + wc;
#pragma unroll
        for (int m = 0; m < 4; ++m)
#pragma unroll
            for (int j = 0; j < 4; ++j) {
                int row = m0 + wr * 64 + m * 16 + jrow4 + j;
                int b = row / Nrows;
                const float* qpb = qp + (long)b * H_;
                float p = 0.f;
#pragma unroll
                for (int n = 0; n < 4; ++n)
                    p += tanhf(qpb[cols[n]] + acc[m][n][j]) * vv[n];
                p += __shfl_xor(p, 1); p += __shfl_xor(p, 2);
                p += __shfl_xor(p, 4); p += __shfl_xor(p, 8);
                if (li == 0) sout[(long)slot * Mtot + row] = p;
            }
    }
}

// ---------------------------------------------------------------------------
// Softmax weights: combine 8 deterministic partials, mask, softmax-normalize.
// grid (B, 2): y==0 node set, y==1 edge set.
__global__ __launch_bounds__(256) void softmax_w_kernel(
    const float* __restrict__ sp_n, const float* __restrict__ sp_e,
    const float* __restrict__ maskbuf, float* __restrict__ wn, float* __restrict__ we)
{
    __shared__ float sw[NEK_];
    __shared__ float red[256];
    int b = blockIdx.x, tid = threadIdx.x, set = blockIdx.y;
    const float* sp = set ? sp_e : sp_n;
    float* wout = set ? we : wn;
    int N = set ? NEK_ : NN_;
    long Mtot = set ? (long)B_ * NEK_ : (long)B_ * NN_;

    float lmax = -3.0e38f;
    for (int n = tid; n < N; n += 256) {
        long row = (long)b * N + n;
        float x = 0.f;
#pragma unroll
        for (int s = 0; s < 8; ++s) x += sp[(long)s * Mtot + row];
        if (!set && n >= NO_ && maskbuf[(long)b * NK_ + (n - NO_)] == 0.f) x = -1e30f;
        sw[n] = x;
        lmax = fmaxf(lmax, x);
    }
    red[tid] = lmax; __syncthreads();
    for (int st = 128; st > 0; st >>= 1) {
        if (tid < st) red[tid] = fmaxf(red[tid], red[tid + st]);
        __syncthreads();
    }
    float mx = red[0]; __syncthreads();

    float lsum = 0.f;
    for (int n = tid; n < N; n += 256) {
        float e = expf(sw[n] - mx);
        sw[n] = e;
        lsum += e;
    }
    red[tid] = lsum; __syncthreads();
    for (int st = 128; st > 0; st >>= 1) {
        if (tid < st) red[tid] += red[tid + st];
        __syncthreads();
    }
    float invZ = 1.0f / red[0];
    __syncthreads();
    for (int n = tid; n < N; n += 256)
        wout[(long)b * N + n] = sw[n] * invZ;
}

// ---------------------------------------------------------------------------
// Weighted key sum, split over n: grid (B, SP). Thread: 8 cols x N/SP/4 rows.
// Deterministic partials [SP][B][512].
template<int SP>
__global__ __launch_bounds__(256) void wsum_kernel(
    const float* __restrict__ w, const short* __restrict__ keys,
    float* __restrict__ partial, int N)
{
    __shared__ float red[4][512];
    int b = blockIdx.x, sp = blockIdx.y, tid = threadIdx.x;
    int c8 = (tid & 63) * 8, rsub = tid >> 6;
    int per = (N + SP - 1) / SP;
    int n0 = sp * per, n1 = min(n0 + per, N);
    float acc[8] = {0.f,0.f,0.f,0.f,0.f,0.f,0.f,0.f};
    for (int n = n0 + rsub; n < n1; n += 4) {
        float wv = w[(long)b * N + n];
        bf16x8 k = *(const bf16x8*)&keys[((long)b * N + n) * H_ + c8];
#pragma unroll
        for (int j = 0; j < 8; ++j) acc[j] = fmaf(wv, bf2f(k[j]), acc[j]);
    }
    *(float4*)&red[rsub][c8]     = *(float4*)acc;
    *(float4*)&red[rsub][c8 + 4] = *(float4*)(acc + 4);
    __syncthreads();
    if (rsub == 0) {
        float o[8];
#pragma unroll
        for (int j = 0; j < 8; ++j)
            o[j] = red[0][c8 + j] + red[1][c8 + j] + red[2][c8 + j] + red[3][c8 + j];
        float* op = &partial[((long)sp * B_ + b) * H_ + c8];
        *(float4*)op       = *(float4*)o;
        *(float4*)(op + 4) = *(float4*)(o + 4);
    }
}

// fin = sum over 16 node partials + 16 edge partials. grid (B*H/256).
__global__ __launch_bounds__(256) void fin_reduce_kernel(
    const float* __restrict__ pn, const float* __restrict__ pe, float* __restrict__ fin)
{
    int i = blockIdx.x * 256 + threadIdx.x;
    float s = 0.f;
#pragma unroll
    for (int sp = 0; sp < 16; ++sp)
        s += pn[(long)sp * B_ * H_ + i] + pe[(long)sp * B_ * H_ + i];
    fin[i] = s;
}

// ---------------------------------------------------------------------------
// K-split matvec over all 32 batch rows: grid (ceil(C/256), E/CHUNK, nsets).
// Each block: cols [bx*256,+256), k-slice [by*CHUNK,+CHUNK), all 32 batches.
// Writes deterministic partials p[ks][b][c]; kreduce sums + bias + act.
template<int E, int CHUNK>
__global__ __launch_bounds__(256) void kmatvec_kernel(
    const float* __restrict__ in, const float* __restrict__ Wa,
    const float* __restrict__ Wb, float* __restrict__ pa,
    float* __restrict__ pb, int C)
{
    __shared__ float ins[32 * CHUNK];
    int tid = threadIdx.x;
    int ks = blockIdx.y, k0 = ks * CHUNK;
    const float* W   = (blockIdx.z == 0) ? Wa : Wb;
    float* partial   = (blockIdx.z == 0) ? pa : pb;
    for (int t = tid; t < 32 * CHUNK; t += 256) {
        int b = t / CHUNK, k = t - b * CHUNK;
        ins[t] = in[(long)b * E + k0 + k];
    }
    __syncthreads();
    int c = blockIdx.x * 256 + tid;
    if (c >= C) return;
    float acc[32];
#pragma unroll
    for (int b = 0; b < 32; ++b) acc[b] = 0.f;
    for (int k = 0; k < CHUNK; ++k) {
        float wv = W[(long)(k0 + k) * C + c];
#pragma unroll
        for (int b = 0; b < 32; ++b)
            acc[b] = fmaf(ins[b * CHUNK + k], wv, acc[b]);
    }
#pragma unroll
    for (int b = 0; b < 32; ++b)
        partial[((long)ks * 32 + b) * C + c] = acc[b];
}

// out[b,c] = act(bias[c] + sum_ks p[ks][b][c]); grid (ceil(32*C/256), nsets)
template<int ACT, int KS>
__global__ __launch_bounds__(256) void kreduce_kernel(
    const float* __restrict__ pa, const float* __restrict__ pb,
    const float* __restrict__ biasa, const float* __restrict__ biasb,
    float* __restrict__ oa, float* __restrict__ ob, int C)
{
    int set = blockIdx.y;
    const float* p    = set ? pb : pa;
    const float* bias = set ? biasb : biasa;
    float* o          = set ? ob : oa;
    long i = (long)blockIdx.x * 256 + threadIdx.x;   // over 32*C
    if (i >= 32L * C) return;
    int c = (int)(i % C);
    float s = bias ? bias[c] : 0.f;
#pragma unroll
    for (int ks = 0; ks < KS; ++ks) s += p[(long)ks * 32 * C + i];
    o[i] = (ACT == 1) ? tanhf(s) : s;
}

// ---------------------------------------------------------------------------
extern "C" void kernel_launch(void* const* d_in, const int* in_sizes, int n_in,
                              void* d_out, int out_size, void* d_ws, size_t ws_size,
                              hipStream_t stream)
{
    (void)in_sizes; (void)n_in; (void)out_size; (void)ws_size;

    const float* img_feat  = (const float*)d_in[0];
    const float* img_loc   = (const float*)d_in[1];
    const int*   id1       = (const int*)d_in[2];
    const int*   id2       = (const int*)d_in[3];
    const int*   kg_entity = (const int*)d_in[4];
    const int*   kg_edge   = (const int*)d_in[7];
    const int*   r_nodes   = (const int*)d_in[8];
    const float* embed     = (const float*)d_in[11];
    const float* W_lang    = (const float*)d_in[12];
    const float* b_lang    = (const float*)d_in[13];
    const float* W_img     = (const float*)d_in[14];
    const float* b_img     = (const float*)d_in[15];
    const float* W_loc     = (const float*)d_in[16];
    const float* b_loc     = (const float*)d_in[17];
    const float* W_rel     = (const float*)d_in[18];
    const float* b_rel     = (const float*)d_in[19];
    const float* Wq_n      = (const float*)d_in[20];
    const float* Wk_n      = (const float*)d_in[21];
    const float* v_n       = (const float*)d_in[22];
    const float* Wq_e      = (const float*)d_in[23];
    const float* Wk_e      = (const float*)d_in[24];
    const float* v_e       = (const float*)d_in[25];
    const float* W1        = (const float*)d_in[26];
    const float* b1        = (const float*)d_in[27];
    const float* W2        = (const float*)d_in[28];
    const float* b2        = (const float*)d_in[29];
    float* out = (float*)d_out;

    char* ws = (char*)d_ws;
    size_t off = 0;
    auto allocS = [&](size_t n) { short* p = (short*)(ws + off); off += ((n * 2 + 255) & ~255ULL); return p; };
    auto allocF = [&](size_t n) { float* p = (float*)(ws + off); off += ((n * 4 + 255) & ~255ULL); return p; };

    short* img_feat_bf = allocS((size_t)B_ * NO_ * IMG_);      // 13 MB
    short* embed_bf    = allocS((size_t)10000 * EMB_ + 16);    // 6 MB (+tail pad)
    short* Wp_img      = allocS((size_t)4 * 64 * 4096);
    short* Wp_rel      = allocS((size_t)4 * 32 * 4096);
    short* Wp_kn       = allocS((size_t)4 * 16 * 4096);
    short* Wp_ke       = allocS((size_t)4 * 16 * 4096);
    short* Wp_lang     = allocS((size_t)4 * 10 * 4096);
    short* img_f_bf    = allocS((size_t)B_ * NO_ * H_);
    short* node_keys   = allocS((size_t)B_ * NN_ * H_);        // 36 MB
    short* edge_keys   = allocS((size_t)B_ * NEK_ * H_);       // 52 MB
    short* pooled_n    = allocS((size_t)B_ * NK_ * 320);       // 20.5 MB
    short* pooled_e    = allocS((size_t)B_ * KE_ * 320);       // 20.5 MB
    short* pooled_r    = allocS((size_t)128 * 320);
    float* rfeat   = allocF((size_t)B_ * H_);
    float* qp_n    = allocF((size_t)B_ * H_);
    float* qp_e    = allocF((size_t)B_ * H_);
    float* mask_kg = allocF((size_t)B_ * NK_);
    float* sp_n    = allocF((size_t)8 * B_ * NN_);             // score partials
    float* sp_e    = allocF((size_t)8 * B_ * NEK_);
    float* wn      = allocF((size_t)B_ * NN_);                 // softmax weights
    float* we      = allocF((size_t)B_ * NEK_);
    float* pn      = allocF((size_t)16 * B_ * H_);             // wsum partials
    float* pe      = allocF((size_t)16 * B_ * H_);
    float* fin     = allocF((size_t)B_ * H_);
    float* hid     = allocF((size_t)B_ * H_);
    float* pq_n    = allocF((size_t)16 * B_ * MID_);           // kmatvec partials
    float* pq_e    = allocF((size_t)16 * B_ * MID_);
    float* ph1     = allocF((size_t)16 * B_ * MID_);
    float* ph2     = allocF((size_t)16 * B_ * C_);             // 6.1 MB

    // --- weight prep + input conversion ---
    cvt_bf16_kernel<<<(B_ * NO_ * IMG_ / 8 + 255) / 256, 256, 0, stream>>>(
        img_feat, img_feat_bf, (long)B_ * NO_ * IMG_);
    cvt_bf16_kernel<<<(10000 * EMB_ / 8 + 255) / 256, 256, 0, stream>>>(
        embed, embed_bf, (long)10000 * EMB_);
    wprep_kernel<<<512, 256, 0, stream>>>(W_img,  Wp_img,  IMG_, 64);
    wprep_kernel<<<256, 256, 0, stream>>>(W_rel,  Wp_rel,  1024, 32);
    wprep_kernel<<<128, 256, 0, stream>>>(Wk_n,   Wp_kn,   512,  16);
    wprep_kernel<<<128, 256, 0, stream>>>(Wk_e,   Wp_ke,   512,  16);
    wprep_kernel<<< 80, 256, 0, stream>>>(W_lang, Wp_lang, EMB_, 10);

    // --- pooled embeddings (gather phase, high occupancy) ---
    pool_kernel<<<B_ * NK_ / 32, 256, 0, stream>>>(
        kg_entity, L_, 0, embed_bf, pooled_n, mask_kg, B_ * NK_);
    pool_kernel<<<B_ * KE_ / 32, 256, 0, stream>>>(
        kg_edge, L_, 0, embed_bf, pooled_e, nullptr, B_ * KE_);
    pool_kernel<<<4, 256, 0, stream>>>(
        r_nodes, R_ * L_, (R_ - 1) * L_, embed_bf, pooled_r, nullptr, B_);

    // --- lang projections (MFMA GEMM phase) ---
    keys_gemm_kernel<0><<<dim3(B_ * NK_ / 128, 4), 256, 0, stream>>>(
        pooled_n, Wp_lang, b_lang, node_keys, NK_, (long)NN_ * H_, (long)NO_ * H_,
        B_ * NK_);
    keys_gemm_kernel<0><<<dim3(B_ * KE_ / 128, 4), 256, 0, stream>>>(
        pooled_e, Wp_lang, b_lang, edge_keys, KE_, (long)NEK_ * H_, (long)NE_ * H_,
        B_ * KE_);
    keys_gemm_kernel<1><<<dim3(1, 4), 256, 0, stream>>>(
        pooled_r, Wp_lang, b_lang, rfeat, 1, (long)H_, 0L, B_);

    // --- qp for root program node (fused pair, K-split) ---
    kmatvec_kernel<H_, 32><<<dim3(2, 16, 2), 256, 0, stream>>>(
        rfeat, Wq_n, Wq_e, pq_n, pq_e, MID_);
    kreduce_kernel<0, 16><<<dim3(B_ * MID_ / 256, 2), 256, 0, stream>>>(
        pq_n, pq_e, nullptr, nullptr, qp_n, qp_e, MID_);

    // --- image branches ---
    mfma_gemm_kernel<0, 0, 64><<<dim3(B_ * NO_ / 128, 4), 256, 0, stream>>>(
        img_feat_bf, IMG_, Wp_img, nullptr, nullptr, nullptr,
        b_img, b_loc, img_loc, W_loc, nullptr, nullptr,
        img_f_bf, node_keys, nullptr, 0, 0);
    mfma_gemm_kernel<2, 1, 32><<<dim3(B_ * NE_ / 128, 4), 256, 0, stream>>>(
        nullptr, 0, Wp_rel, id1, id2, img_f_bf,
        b_rel, nullptr, nullptr, nullptr, nullptr, nullptr,
        edge_keys, nullptr, nullptr, 0, 0);

    // --- fused keys@Wk + tanh-attention score partials ---
    mfma_gemm_kernel<0, 2, 16><<<dim3(B_ * NN_ / 128, 4), 256, 0, stream>>>(
        node_keys, H_, Wp_kn, nullptr, nullptr, nullptr,
        nullptr, nullptr, nullptr, nullptr, qp_n, v_n,
        nullptr, nullptr, sp_n, NN_, B_ * NN_);
    mfma_gemm_kernel<0, 2, 16><<<dim3(B_ * NEK_ / 128, 4), 256, 0, stream>>>(
        edge_keys, H_, Wp_ke, nullptr, nullptr, nullptr,
        nullptr, nullptr, nullptr, nullptr, qp_e, v_e,
        nullptr, nullptr, sp_e, NEK_, B_ * NEK_);

    // --- softmax weights + parallel weighted sums ---
    softmax_w_kernel<<<dim3(B_, 2), 256, 0, stream>>>(sp_n, sp_e, mask_kg, wn, we);
    wsum_kernel<16><<<dim3(B_, 16), 256, 0, stream>>>(wn, node_keys, pn, NN_);
    wsum_kernel<16><<<dim3(B_, 16), 256, 0, stream>>>(we, edge_keys, pe, NEK_);
    fin_reduce_kernel<<<B_ * H_ / 256, 256, 0, stream>>>(pn, pe, fin);

    // --- head: hid = tanh(fin@W1 + b1); out = hid@W2 + b2 ---
    kmatvec_kernel<H_, 32><<<dim3(2, 16, 1), 256, 0, stream>>>(
        fin, W1, W1, ph1, ph1, MID_);
    kreduce_kernel<1, 16><<<dim3(B_ * MID_ / 256, 1), 256, 0, stream>>>(
        ph1, ph1, b1, b1, hid, hid, MID_);
    kmatvec_kernel<MID_, 32><<<dim3((C_ + 255) / 256, 16, 1), 256, 0, stream>>>(
        hid, W2, W2, ph2, ph2, C_);
    kreduce_kernel<0, 16><<<dim3((B_ * C_ + 255) / 256, 1), 256, 0, stream>>>(
        ph2, ph2, b2, b2, out, out, C_);
}

// Round 9
// 448.146 us; speedup vs baseline: 1.1520x; 1.1520x over previous
//
#include <hip/hip_runtime.h>
#include <hip/hip_bf16.h>
#include <math.h>

// Problem dims
#define B_   32
#define NO_  100
#define NE_  600
#define NK_  1000
#define KE_  1000
#define L_   8
#define R_   8
#define H_   512
#define IMG_ 2048
#define LOC_ 5
#define EMB_ 300
#define MID_ 512
#define C_   3000
#define PAD_ 1

#define NN_  (NO_ + NK_)   // 1100 node keys
#define NEK_ (NE_ + KE_)   // 1600 edge keys

typedef __attribute__((ext_vector_type(8))) short bf16x8;
typedef __attribute__((ext_vector_type(4))) float f32x4;

__device__ __forceinline__ float4 ldf4(const float* p) { return *(const float4*)p; }

__device__ __forceinline__ float bf2f(short s) {
    unsigned u = ((unsigned)(unsigned short)s) << 16;
    float f; __builtin_memcpy(&f, &u, 4); return f;
}
__device__ __forceinline__ short f2bf(float f) {
    unsigned u; __builtin_memcpy(&u, &f, 4);
    u = (u + 0x7fffu + ((u >> 16) & 1u)) >> 16;   // round-nearest-even
    return (short)u;
}

// Direct global->LDS 16B/lane. LDS dest wave-uniform base (+lane*16 by HW);
// global src per-lane.
__device__ __forceinline__ void gload16(const void* g, void* l) {
    __builtin_amdgcn_global_load_lds(
        (__attribute__((address_space(1))) void*)(g),
        (__attribute__((address_space(3))) void*)(l), 16, 0, 0);
}

// ---------------------------------------------------------------------------
// W_prep: f32 W[K][512] -> bf16 tiles [NB=4][KS][4 kg][128 nl][8 j]
// entry = W[ks*32+kg*8+j][nb*128+nl]  (zeros for k >= K)
__global__ __launch_bounds__(256) void wprep_kernel(
    const float* __restrict__ W, short* __restrict__ Wp, int K, int KS)
{
    int idx = blockIdx.x * 256 + threadIdx.x;
    int total = 4 * KS * 4 * 128;
    if (idx >= total) return;
    int nl = idx & 127;
    int kg = (idx >> 7) & 3;
    int t  = idx >> 9;            // nb*KS + ks
    int ks = t % KS;
    int nb = t / KS;
    int n = nb * 128 + nl;
    short o[8];
#pragma unroll
    for (int j = 0; j < 8; ++j) {
        int k = ks * 32 + kg * 8 + j;
        o[j] = (k < K) ? f2bf(W[(long)k * H_ + n]) : (short)0;
    }
    *(uint4*)&Wp[(long)idx * 8] = *(uint4*)o;
}

// f32 -> bf16 elementwise (n multiple of 8)
__global__ __launch_bounds__(256) void cvt_bf16_kernel(
    const float* __restrict__ src, short* __restrict__ dst, long n)
{
    long i = ((long)blockIdx.x * 256 + threadIdx.x) * 8;
    if (i >= n) return;
    float4 a = ldf4(src + i), b = ldf4(src + i + 4);
    short o[8] = { f2bf(a.x), f2bf(a.y), f2bf(a.z), f2bf(a.w),
                   f2bf(b.x), f2bf(b.y), f2bf(b.z), f2bf(b.w) };
    *(uint4*)&dst[i] = *(uint4*)o;
}

// ---------------------------------------------------------------------------
// Pool: masked mean of bf16 embeddings, two token sources split at `split`.
// 32 rows/block, minimal LDS, high occupancy. Writes pooled [row][320] bf16
// (zeros past EMB, PAD-rows -> zeros) + mask for rows < split when given.
__global__ __launch_bounds__(256) void pool_kernel(
    const int* __restrict__ tokA, const int* __restrict__ tokB, int split,
    int tok_stride, int tok_off, const short* __restrict__ embed_bf,
    short* __restrict__ pooled, float* __restrict__ maskout, int nrows)
{
    __shared__ int   toks[32][8];
    __shared__ float rinv[32];
    int tid = threadIdx.x, base = blockIdx.x * 32;
    const int* tokens; int local;
    if (base < split) { tokens = tokA; local = base; }
    else              { tokens = tokB; local = base - split; }
    {
        int r = tid >> 3, t = tid & 7;
        int i = base + r;
        toks[r][t] = (i < nrows) ? tokens[tok_off + (long)(local + r) * tok_stride + t] : PAD_;
    }
    __syncthreads();
    if (tid < 32) {
        int c = 0;
#pragma unroll
        for (int t = 0; t < 8; ++t) c += (toks[tid][t] != PAD_);
        rinv[tid] = 1.0f / fmaxf((float)c, 1.0f);
        int i = base + tid;
        if (maskout && i < split && i < nrows) maskout[i] = (c > 0) ? 1.0f : 0.0f;
    }
    __syncthreads();

    for (int task = tid; task < 32 * 40; task += 256) {
        int r = task / 40, kg = task - r * 40;    // row, 8-elem chunk
        float s[8] = {0.f,0.f,0.f,0.f,0.f,0.f,0.f,0.f};
        if (kg < 38) {                            // EMB=300 -> chunks 0..37
#pragma unroll
            for (int t = 0; t < 8; ++t) {
                int tok = toks[r][t];
                if (tok != PAD_) {
                    bf16x8 e = *(const bf16x8*)&embed_bf[(long)tok * EMB_ + kg * 8];
#pragma unroll
                    for (int j = 0; j < 8; ++j) s[j] += bf2f(e[j]);
                }
            }
        }
        float iv = rinv[r];
        short o[8];
#pragma unroll
        for (int j = 0; j < 8; ++j) {
            float v = s[j] * iv;
            if (kg == 37 && j >= 4) v = 0.f;      // elems 300..303 are overread
            o[j] = f2bf(v);
        }
        *(uint4*)&pooled[(long)(base + r) * 320 + kg * 8] = *(uint4*)o;
    }
}

// ---------------------------------------------------------------------------
// Keys GEMM: pooled[rows][320] @ W_lang -> tanh(+bias) -> keys.
// 128x128 tile, 4 waves, BK=64 single-buffered LDS via global_load_lds:
// per chunk {stage 8x gload16/wave, barrier, 32 MFMA, barrier} -> only
// NCH=5 latency exposures per block (vs 10).
// DUAL=1: rows [0,32000) -> node_keys, [32000,64000) -> edge_keys.
// DUAL=0: row i -> out[i*H] (rfeat path), f32 out.
template<int DUAL, int OUTF32>
__global__ __launch_bounds__(256) void keys_gemm_kernel(
    const short* __restrict__ A, const short* __restrict__ Wp,
    const float* __restrict__ bias,
    void* __restrict__ outA, short* __restrict__ outB, int nrows)
{
    const int NCH = 5;                         // K=320 in chunks of 64
    __shared__ __align__(16) short As[8192];   // [8 g][128 row][8]
    __shared__ __align__(16) short Bs[8192];   // [2 s][4 kg][128 nl][8]
    int tid = threadIdx.x;
    int m0 = blockIdx.x * 128, nb = blockIdx.y, n0 = nb * 128;
    int w = tid >> 6, l = tid & 63, wr = w >> 1, wc = w & 1;
    const short* wslab = Wp + (long)nb * (NCH * 2) * 4096;

    f32x4 acc[4][4];
#pragma unroll
    for (int m = 0; m < 4; ++m)
#pragma unroll
        for (int n = 0; n < 4; ++n)
#pragma unroll
            for (int k = 0; k < 4; ++k) acc[m][n][k] = 0.f;

    int kg = l >> 4, li = l & 15;
    for (int t = 0; t < NCH; ++t) {
#pragma unroll
        for (int j = 0; j < 4; ++j) {
            int c = w * 4 + j;
            int g = c >> 1, h2 = c & 1;
            const short* ga = A + (long)(m0 + h2 * 64 + l) * 320 + t * 64 + g * 8;
            gload16(ga, As + c * 512);
            gload16(wslab + ((long)t * 2) * 4096 + c * 512 + l * 8, Bs + c * 512);
        }
        __syncthreads();                       // loads complete (vmcnt drain)
#pragma unroll
        for (int s = 0; s < 2; ++s) {
            bf16x8 af[4], bfr[4];
#pragma unroll
            for (int m = 0; m < 4; ++m)
                af[m] = *(const bf16x8*)&As[(s * 4 + kg) * 1024 + (wr * 64 + m * 16 + li) * 8];
#pragma unroll
            for (int n = 0; n < 4; ++n)
                bfr[n] = *(const bf16x8*)&Bs[(s * 4 + kg) * 1024 + (wc * 64 + n * 16 + li) * 8];
#pragma unroll
            for (int m = 0; m < 4; ++m)
#pragma unroll
                for (int n = 0; n < 4; ++n)
                    acc[m][n] = __builtin_amdgcn_mfma_f32_16x16x32_bf16(af[m], bfr[n], acc[m][n], 0, 0, 0);
        }
        __syncthreads();                       // reads done before next stage
    }

    int jrow4 = (l >> 4) * 4;
    float bv[4];
#pragma unroll
    for (int n = 0; n < 4; ++n) bv[n] = bias[n0 + wc * 64 + n * 16 + li];
#pragma unroll
    for (int m = 0; m < 4; ++m)
#pragma unroll
        for (int j = 0; j < 4; ++j) {
            int i = m0 + wr * 64 + m * 16 + jrow4 + j;
            if (i >= nrows) continue;
#pragma unroll
            for (int n = 0; n < 4; ++n) {
                int col = n0 + wc * 64 + n * 16 + li;
                float val = tanhf(acc[m][n][j] + bv[n]);
                if (DUAL) {
                    if (i < B_ * NK_) {
                        int b = i / NK_, k = i - b * NK_;
                        ((short*)outA)[(long)b * (NN_ * H_) + (long)(NO_ + k) * H_ + col] = f2bf(val);
                    } else {
                        int i2 = i - B_ * NK_;
                        int b = i2 / KE_, k = i2 - b * KE_;
                        outB[(long)b * (NEK_ * H_) + (long)(NE_ + k) * H_ + col] = f2bf(val);
                    }
                } else {
                    long idx = (long)i * H_ + col;
                    if (OUTF32) ((float*)outA)[idx] = val;
                    else        ((short*)outA)[idx] = f2bf(val);
                }
            }
        }
}

// ---------------------------------------------------------------------------
// MFMA GEMM: 128x128 tile, BK=64 single-buffered (NCH chunks of 64), 4 waves,
// grid (M/128, 4). Staging via global_load_lds; 2 barriers per chunk.
// A: bf16 row-major (AV=0) or gathered img_f rows (AV=2, K=1024 two halves).
// EP: 0 img_node (img_f + node_keys w/ loc), 1 img_edge, 2 score partials.
template<int AV, int EP, int NCH>
__global__ __launch_bounds__(256) void mfma_gemm_kernel(
    const short* __restrict__ A, int lda, const short* __restrict__ Wp,
    const int* __restrict__ id1, const int* __restrict__ id2,
    const short* __restrict__ Agather,
    const float* __restrict__ bias, const float* __restrict__ bias2,
    const float* __restrict__ loc, const float* __restrict__ Wloc,
    const float* __restrict__ qp, const float* __restrict__ vvec,
    short* __restrict__ out0, short* __restrict__ out1,
    float* __restrict__ sout, int Nrows, int Mtot)
{
    __shared__ __align__(16) short As[8192];   // [8 g][128 row][8]
    __shared__ __align__(16) short Bs[8192];   // [2 s][4 kg][128 nl][8]
    int tid = threadIdx.x;
    int m0 = blockIdx.x * 128, nb = blockIdx.y, n0 = nb * 128;
    int w = tid >> 6, l = tid & 63, wr = w >> 1, wc = w & 1;

    int r1[2], r2[2];                          // AV=2 gathered rows (per lane)
    if (AV == 2) {
#pragma unroll
        for (int i = 0; i < 2; ++i) {
            int row = m0 + i * 64 + l;
            int b = row / NE_;
            r1[i] = b * NO_ + id1[row];
            r2[i] = b * NO_ + id2[row];
        }
    }
    const short* wslab = Wp + (long)nb * (NCH * 2) * 4096;

    f32x4 acc[4][4];
#pragma unroll
    for (int m = 0; m < 4; ++m)
#pragma unroll
        for (int n = 0; n < 4; ++n)
#pragma unroll
            for (int k = 0; k < 4; ++k) acc[m][n][k] = 0.f;

    int kg = l >> 4, li = l & 15;
    for (int t = 0; t < NCH; ++t) {
#pragma unroll
        for (int j = 0; j < 4; ++j) {
            int c = w * 4 + j;
            int g = c >> 1, h2 = c & 1;
            const short* ga;
            if (AV == 0) {
                ga = A + (long)(m0 + h2 * 64 + l) * lda + t * 64 + g * 8;
            } else {
                int kk = t * 64 + g * 8;
                int row = (kk < 512) ? r1[h2] : r2[h2];
                ga = Agather + (long)row * 512 + (kk & 511);
            }
            gload16(ga, As + c * 512);
            gload16(wslab + ((long)t * 2) * 4096 + c * 512 + l * 8, Bs + c * 512);
        }
        __syncthreads();                       // loads complete (vmcnt drain)
#pragma unroll
        for (int s = 0; s < 2; ++s) {
            bf16x8 af[4], bfr[4];
#pragma unroll
            for (int m = 0; m < 4; ++m)
                af[m] = *(const bf16x8*)&As[(s * 4 + kg) * 1024 + (wr * 64 + m * 16 + li) * 8];
#pragma unroll
            for (int n = 0; n < 4; ++n)
                bfr[n] = *(const bf16x8*)&Bs[(s * 4 + kg) * 1024 + (wc * 64 + n * 16 + li) * 8];
#pragma unroll
            for (int m = 0; m < 4; ++m)
#pragma unroll
                for (int n = 0; n < 4; ++n)
                    acc[m][n] = __builtin_amdgcn_mfma_f32_16x16x32_bf16(af[m], bfr[n], acc[m][n], 0, 0, 0);
        }
        __syncthreads();                       // reads done before next stage
    }

    int jrow4 = (l >> 4) * 4;
    if (EP == 0) {                             // img_node
        float bi[4], bl[4], wl[4][5];
#pragma unroll
        for (int n = 0; n < 4; ++n) {
            int col = n0 + wc * 64 + n * 16 + li;
            bi[n] = bias[col]; bl[n] = bias2[col];
#pragma unroll
            for (int j5 = 0; j5 < 5; ++j5) wl[n][j5] = Wloc[j5 * H_ + col];
        }
#pragma unroll
        for (int m = 0; m < 4; ++m)
#pragma unroll
            for (int j = 0; j < 4; ++j) {
                int row = m0 + wr * 64 + m * 16 + jrow4 + j;
                int b = row / NO_, o = row - b * NO_;
                float lv[5];
#pragma unroll
                for (int j5 = 0; j5 < 5; ++j5) lv[j5] = loc[(long)row * 5 + j5];
#pragma unroll
                for (int n = 0; n < 4; ++n) {
                    int col = n0 + wc * 64 + n * 16 + li;
                    float val = acc[m][n][j] + bi[n];
                    out0[(long)row * H_ + col] = f2bf(val);
                    float nk = val + bl[n];
#pragma unroll
                    for (int j5 = 0; j5 < 5; ++j5) nk = fmaf(lv[j5], wl[n][j5], nk);
                    out1[((long)b * NN_ + o) * H_ + col] = f2bf(nk);
                }
            }
    } else if (EP == 1) {                      // img_edge
        float bi[4];
#pragma unroll
        for (int n = 0; n < 4; ++n) bi[n] = bias[n0 + wc * 64 + n * 16 + li];
#pragma unroll
        for (int m = 0; m < 4; ++m)
#pragma unroll
            for (int j = 0; j < 4; ++j) {
                int row = m0 + wr * 64 + m * 16 + jrow4 + j;
                int b = row / NE_, e = row - b * NE_;
#pragma unroll
                for (int n = 0; n < 4; ++n) {
                    int col = n0 + wc * 64 + n * 16 + li;
                    out0[((long)b * NEK_ + e) * H_ + col] = f2bf(acc[m][n][j] + bi[n]);
                }
            }
    } else {                                   // score partials
        float vv[4];
        int cols[4];
#pragma unroll
        for (int n = 0; n < 4; ++n) {
            cols[n] = n0 + wc * 64 + n * 16 + li;
            vv[n] = vvec[cols[n]];
        }
        int slot = nb * 2 + wc;
#pragma unroll
        for (int m = 0; m < 4; ++m)
#pragma unroll
            for (int j = 0; j < 4; ++j) {
                int row = m0 + wr * 64 + m * 16 + jrow4 + j;
                int b = row / Nrows;
                const float* qpb = qp + (long)b * H_;
                float p = 0.f;
#pragma unroll
                for (int n = 0; n < 4; ++n)
                    p += tanhf(qpb[cols[n]] + acc[m][n][j]) * vv[n];
                p += __shfl_xor(p, 1); p += __shfl_xor(p, 2);
                p += __shfl_xor(p, 4); p += __shfl_xor(p, 8);
                if (li == 0) sout[(long)slot * Mtot + row] = p;
            }
    }
}

// ---------------------------------------------------------------------------
// Softmax weights: combine 8 deterministic partials, mask, softmax-normalize.
// grid (B, 2): y==0 node set, y==1 edge set.
__global__ __launch_bounds__(256) void softmax_w_kernel(
    const float* __restrict__ sp_n, const float* __restrict__ sp_e,
    const float* __restrict__ maskbuf, float* __restrict__ wn, float* __restrict__ we)
{
    __shared__ float sw[NEK_];
    __shared__ float red[256];
    int b = blockIdx.x, tid = threadIdx.x, set = blockIdx.y;
    const float* sp = set ? sp_e : sp_n;
    float* wout = set ? we : wn;
    int N = set ? NEK_ : NN_;
    long Mtot = set ? (long)B_ * NEK_ : (long)B_ * NN_;

    float lmax = -3.0e38f;
    for (int n = tid; n < N; n += 256) {
        long row = (long)b * N + n;
        float x = 0.f;
#pragma unroll
        for (int s = 0; s < 8; ++s) x += sp[(long)s * Mtot + row];
        if (!set && n >= NO_ && maskbuf[(long)b * NK_ + (n - NO_)] == 0.f) x = -1e30f;
        sw[n] = x;
        lmax = fmaxf(lmax, x);
    }
    red[tid] = lmax; __syncthreads();
    for (int st = 128; st > 0; st >>= 1) {
        if (tid < st) red[tid] = fmaxf(red[tid], red[tid + st]);
        __syncthreads();
    }
    float mx = red[0]; __syncthreads();

    float lsum = 0.f;
    for (int n = tid; n < N; n += 256) {
        float e = expf(sw[n] - mx);
        sw[n] = e;
        lsum += e;
    }
    red[tid] = lsum; __syncthreads();
    for (int st = 128; st > 0; st >>= 1) {
        if (tid < st) red[tid] += red[tid + st];
        __syncthreads();
    }
    float invZ = 1.0f / red[0];
    __syncthreads();
    for (int n = tid; n < N; n += 256)
        wout[(long)b * N + n] = sw[n] * invZ;
}

// ---------------------------------------------------------------------------
// Weighted key sum, split over n: grid (B, SP). Thread: 8 cols x N/SP/4 rows.
// Deterministic partials [SP][B][512].
template<int SP>
__global__ __launch_bounds__(256) void wsum_kernel(
    const float* __restrict__ w, const short* __restrict__ keys,
    float* __restrict__ partial, int N)
{
    __shared__ float red[4][512];
    int b = blockIdx.x, sp = blockIdx.y, tid = threadIdx.x;
    int c8 = (tid & 63) * 8, rsub = tid >> 6;
    int per = (N + SP - 1) / SP;
    int n0 = sp * per, n1 = min(n0 + per, N);
    float acc[8] = {0.f,0.f,0.f,0.f,0.f,0.f,0.f,0.f};
    for (int n = n0 + rsub; n < n1; n += 4) {
        float wv = w[(long)b * N + n];
        bf16x8 k = *(const bf16x8*)&keys[((long)b * N + n) * H_ + c8];
#pragma unroll
        for (int j = 0; j < 8; ++j) acc[j] = fmaf(wv, bf2f(k[j]), acc[j]);
    }
    *(float4*)&red[rsub][c8]     = *(float4*)acc;
    *(float4*)&red[rsub][c8 + 4] = *(float4*)(acc + 4);
    __syncthreads();
    if (rsub == 0) {
        float o[8];
#pragma unroll
        for (int j = 0; j < 8; ++j)
            o[j] = red[0][c8 + j] + red[1][c8 + j] + red[2][c8 + j] + red[3][c8 + j];
        float* op = &partial[((long)sp * B_ + b) * H_ + c8];
        *(float4*)op       = *(float4*)o;
        *(float4*)(op + 4) = *(float4*)(o + 4);
    }
}

// fin = sum over 16 node partials + 16 edge partials. grid (B*H/256).
__global__ __launch_bounds__(256) void fin_reduce_kernel(
    const float* __restrict__ pn, const float* __restrict__ pe, float* __restrict__ fin)
{
    int i = blockIdx.x * 256 + threadIdx.x;
    float s = 0.f;
#pragma unroll
    for (int sp = 0; sp < 16; ++sp)
        s += pn[(long)sp * B_ * H_ + i] + pe[(long)sp * B_ * H_ + i];
    fin[i] = s;
}

// ---------------------------------------------------------------------------
// K-split matvec over all 32 batch rows: grid (ceil(C/256), E/CHUNK, nsets).
// Writes deterministic partials p[ks][b][c]; kreduce sums + bias + act.
template<int E, int CHUNK>
__global__ __launch_bounds__(256) void kmatvec_kernel(
    const float* __restrict__ in, const float* __restrict__ Wa,
    const float* __restrict__ Wb, float* __restrict__ pa,
    float* __restrict__ pb, int C)
{
    __shared__ float ins[32 * CHUNK];
    int tid = threadIdx.x;
    int ks = blockIdx.y, k0 = ks * CHUNK;
    const float* W   = (blockIdx.z == 0) ? Wa : Wb;
    float* partial   = (blockIdx.z == 0) ? pa : pb;
    for (int t = tid; t < 32 * CHUNK; t += 256) {
        int b = t / CHUNK, k = t - b * CHUNK;
        ins[t] = in[(long)b * E + k0 + k];
    }
    __syncthreads();
    int c = blockIdx.x * 256 + tid;
    if (c >= C) return;
    float acc[32];
#pragma unroll
    for (int b = 0; b < 32; ++b) acc[b] = 0.f;
    for (int k = 0; k < CHUNK; ++k) {
        float wv = W[(long)(k0 + k) * C + c];
#pragma unroll
        for (int b = 0; b < 32; ++b)
            acc[b] = fmaf(ins[b * CHUNK + k], wv, acc[b]);
    }
#pragma unroll
    for (int b = 0; b < 32; ++b)
        partial[((long)ks * 32 + b) * C + c] = acc[b];
}

// out[b,c] = act(bias[c] + sum_ks p[ks][b][c]); grid (ceil(32*C/256), nsets)
template<int ACT, int KS>
__global__ __launch_bounds__(256) void kreduce_kernel(
    const float* __restrict__ pa, const float* __restrict__ pb,
    const float* __restrict__ biasa, const float* __restrict__ biasb,
    float* __restrict__ oa, float* __restrict__ ob, int C)
{
    int set = blockIdx.y;
    const float* p    = set ? pb : pa;
    const float* bias = set ? biasb : biasa;
    float* o          = set ? ob : oa;
    long i = (long)blockIdx.x * 256 + threadIdx.x;   // over 32*C
    if (i >= 32L * C) return;
    int c = (int)(i % C);
    float s = bias ? bias[c] : 0.f;
#pragma unroll
    for (int ks = 0; ks < KS; ++ks) s += p[(long)ks * 32 * C + i];
    o[i] = (ACT == 1) ? tanhf(s) : s;
}

// ---------------------------------------------------------------------------
extern "C" void kernel_launch(void* const* d_in, const int* in_sizes, int n_in,
                              void* d_out, int out_size, void* d_ws, size_t ws_size,
                              hipStream_t stream)
{
    (void)in_sizes; (void)n_in; (void)out_size; (void)ws_size;

    const float* img_feat  = (const float*)d_in[0];
    const float* img_loc   = (const float*)d_in[1];
    const int*   id1       = (const int*)d_in[2];
    const int*   id2       = (const int*)d_in[3];
    const int*   kg_entity = (const int*)d_in[4];
    const int*   kg_edge   = (const int*)d_in[7];
    const int*   r_nodes   = (const int*)d_in[8];
    const float* embed     = (const float*)d_in[11];
    const float* W_lang    = (const float*)d_in[12];
    const float* b_lang    = (const float*)d_in[13];
    const float* W_img     = (const float*)d_in[14];
    const float* b_img     = (const float*)d_in[15];
    const float* W_loc     = (const float*)d_in[16];
    const float* b_loc     = (const float*)d_in[17];
    const float* W_rel     = (const float*)d_in[18];
    const float* b_rel     = (const float*)d_in[19];
    const float* Wq_n      = (const float*)d_in[20];
    const float* Wk_n      = (const float*)d_in[21];
    const float* v_n       = (const float*)d_in[22];
    const float* Wq_e      = (const float*)d_in[23];
    const float* Wk_e      = (const float*)d_in[24];
    const float* v_e       = (const float*)d_in[25];
    const float* W1        = (const float*)d_in[26];
    const float* b1        = (const float*)d_in[27];
    const float* W2        = (const float*)d_in[28];
    const float* b2        = (const float*)d_in[29];
    float* out = (float*)d_out;

    char* ws = (char*)d_ws;
    size_t off = 0;
    auto allocS = [&](size_t n) { short* p = (short*)(ws + off); off += ((n * 2 + 255) & ~255ULL); return p; };
    auto allocF = [&](size_t n) { float* p = (float*)(ws + off); off += ((n * 4 + 255) & ~255ULL); return p; };

    short* img_feat_bf = allocS((size_t)B_ * NO_ * IMG_);      // 13 MB
    short* embed_bf    = allocS((size_t)10000 * EMB_ + 16);    // 6 MB (+tail pad)
    short* Wp_img      = allocS((size_t)4 * 64 * 4096);
    short* Wp_rel      = allocS((size_t)4 * 32 * 4096);
    short* Wp_kn       = allocS((size_t)4 * 16 * 4096);
    short* Wp_ke       = allocS((size_t)4 * 16 * 4096);
    short* Wp_lang     = allocS((size_t)4 * 10 * 4096);
    short* img_f_bf    = allocS((size_t)B_ * NO_ * H_);
    short* node_keys   = allocS((size_t)B_ * NN_ * H_);        // 36 MB
    short* edge_keys   = allocS((size_t)B_ * NEK_ * H_);       // 52 MB
    short* pooled      = allocS((size_t)2 * B_ * NK_ * 320);   // 41 MB (node+edge)
    short* pooled_r    = allocS((size_t)128 * 320);
    float* rfeat   = allocF((size_t)B_ * H_);
    float* qp_n    = allocF((size_t)B_ * H_);
    float* qp_e    = allocF((size_t)B_ * H_);
    float* mask_kg = allocF((size_t)B_ * NK_);
    float* sp_n    = allocF((size_t)8 * B_ * NN_);             // score partials
    float* sp_e    = allocF((size_t)8 * B_ * NEK_);
    float* wn      = allocF((size_t)B_ * NN_);                 // softmax weights
    float* we      = allocF((size_t)B_ * NEK_);
    float* pn      = allocF((size_t)16 * B_ * H_);             // wsum partials
    float* pe      = allocF((size_t)16 * B_ * H_);
    float* fin     = allocF((size_t)B_ * H_);
    float* hid     = allocF((size_t)B_ * H_);
    float* pq_n    = allocF((size_t)16 * B_ * MID_);           // kmatvec partials
    float* pq_e    = allocF((size_t)16 * B_ * MID_);
    float* ph1     = allocF((size_t)16 * B_ * MID_);
    float* ph2     = allocF((size_t)16 * B_ * C_);             // 6.1 MB

    // --- weight prep + input conversion ---
    cvt_bf16_kernel<<<(B_ * NO_ * IMG_ / 8 + 255) / 256, 256, 0, stream>>>(
        img_feat, img_feat_bf, (long)B_ * NO_ * IMG_);
    cvt_bf16_kernel<<<(10000 * EMB_ / 8 + 255) / 256, 256, 0, stream>>>(
        embed, embed_bf, (long)10000 * EMB_);
    wprep_kernel<<<512, 256, 0, stream>>>(W_img,  Wp_img,  IMG_, 64);
    wprep_kernel<<<256, 256, 0, stream>>>(W_rel,  Wp_rel,  1024, 32);
    wprep_kernel<<<128, 256, 0, stream>>>(Wk_n,   Wp_kn,   512,  16);
    wprep_kernel<<<128, 256, 0, stream>>>(Wk_e,   Wp_ke,   512,  16);
    wprep_kernel<<< 80, 256, 0, stream>>>(W_lang, Wp_lang, EMB_, 10);

    // --- pooled embeddings (merged node+edge gather, high occupancy) ---
    pool_kernel<<<2 * B_ * NK_ / 32, 256, 0, stream>>>(
        kg_entity, kg_edge, B_ * NK_, L_, 0, embed_bf, pooled, mask_kg, 2 * B_ * NK_);
    pool_kernel<<<4, 256, 0, stream>>>(
        r_nodes, nullptr, 1 << 30, R_ * L_, (R_ - 1) * L_, embed_bf, pooled_r,
        nullptr, B_);

    // --- lang projections (merged keys GEMM, BK=64) ---
    keys_gemm_kernel<1, 0><<<dim3(2 * B_ * NK_ / 128, 4), 256, 0, stream>>>(
        pooled, Wp_lang, b_lang, node_keys, edge_keys, 2 * B_ * NK_);
    keys_gemm_kernel<0, 1><<<dim3(1, 4), 256, 0, stream>>>(
        pooled_r, Wp_lang, b_lang, rfeat, nullptr, B_);

    // --- qp for root program node (fused pair, K-split) ---
    kmatvec_kernel<H_, 32><<<dim3(2, 16, 2), 256, 0, stream>>>(
        rfeat, Wq_n, Wq_e, pq_n, pq_e, MID_);
    kreduce_kernel<0, 16><<<dim3(B_ * MID_ / 256, 2), 256, 0, stream>>>(
        pq_n, pq_e, nullptr, nullptr, qp_n, qp_e, MID_);

    // --- image branches (BK=64) ---
    mfma_gemm_kernel<0, 0, 32><<<dim3(B_ * NO_ / 128, 4), 256, 0, stream>>>(
        img_feat_bf, IMG_, Wp_img, nullptr, nullptr, nullptr,
        b_img, b_loc, img_loc, W_loc, nullptr, nullptr,
        img_f_bf, node_keys, nullptr, 0, 0);
    mfma_gemm_kernel<2, 1, 16><<<dim3(B_ * NE_ / 128, 4), 256, 0, stream>>>(
        nullptr, 0, Wp_rel, id1, id2, img_f_bf,
        b_rel, nullptr, nullptr, nullptr, nullptr, nullptr,
        edge_keys, nullptr, nullptr, 0, 0);

    // --- fused keys@Wk + tanh-attention score partials (BK=64) ---
    mfma_gemm_kernel<0, 2, 8><<<dim3(B_ * NN_ / 128, 4), 256, 0, stream>>>(
        node_keys, H_, Wp_kn, nullptr, nullptr, nullptr,
        nullptr, nullptr, nullptr, nullptr, qp_n, v_n,
        nullptr, nullptr, sp_n, NN_, B_ * NN_);
    mfma_gemm_kernel<0, 2, 8><<<dim3(B_ * NEK_ / 128, 4), 256, 0, stream>>>(
        edge_keys, H_, Wp_ke, nullptr, nullptr, nullptr,
        nullptr, nullptr, nullptr, nullptr, qp_e, v_e,
        nullptr, nullptr, sp_e, NEK_, B_ * NEK_);

    // --- softmax weights + parallel weighted sums ---
    softmax_w_kernel<<<dim3(B_, 2), 256, 0, stream>>>(sp_n, sp_e, mask_kg, wn, we);
    wsum_kernel<16><<<dim3(B_, 16), 256, 0, stream>>>(wn, node_keys, pn, NN_);
    wsum_kernel<16><<<dim3(B_, 16), 256, 0, stream>>>(we, edge_keys, pe, NEK_);
    fin_reduce_kernel<<<B_ * H_ / 256, 256, 0, stream>>>(pn, pe, fin);

    // --- head: hid = tanh(fin@W1 + b1); out = hid@W2 + b2 ---
    kmatvec_kernel<H_, 32><<<dim3(2, 16, 1), 256, 0, stream>>>(
        fin, W1, W1, ph1, ph1, MID_);
    kreduce_kernel<1, 16><<<dim3(B_ * MID_ / 256, 1), 256, 0, stream>>>(
        ph1, ph1, b1, b1, hid, hid, MID_);
    kmatvec_kernel<MID_, 32><<<dim3((C_ + 255) / 256, 16, 1), 256, 0, stream>>>(
        hid, W2, W2, ph2, ph2, C_);
    kreduce_kernel<0, 16><<<dim3((B_ * C_ + 255) / 256, 1), 256, 0, stream>>>(
        ph2, ph2, b2, b2, out, out, C_);
}